// Round 1
// baseline (133.713 us; speedup 1.0000x reference)
//
#include <hip/hip_runtime.h>
#include <math.h>

#define T_N 100000
#define H_N 256

typedef __attribute__((ext_vector_type(8))) __bf16 bf16x8;
typedef __attribute__((ext_vector_type(4))) __bf16 bf16x4;
typedef __attribute__((ext_vector_type(4))) float f32x4;

// ws layout (bytes):
//       0 : WmT bf16 [256][256]   (131072)
//  131072 : proj f32 [256]        (1024)
//  132096 : At   f32 [100000]     (400000)
//  532096 : partials float2[256]  (2048)
//  534144 : lse  f32              (4)

// ---------------------------------------------------------------- prep
__global__ __launch_bounds__(256) void k_prep(const float* __restrict__ Wm,
                                              const float* __restrict__ hc,
                                              const float* __restrict__ W1,
                                              __bf16* __restrict__ WmT,
                                              float* __restrict__ proj,
                                              float* __restrict__ out) {
    const int j = blockIdx.x;   // 0..255 output row of WmT / proj index
    const int t = threadIdx.x;  // 0..255
    // WmT[j][k] = Wm[k][j], converted to bf16 (B^T row-major, k-contiguous)
    WmT[j * H_N + t] = (__bf16)Wm[t * H_N + j];
    // proj[j] = sum_k hc[k] * W1[j][k]
    __shared__ float red[H_N];
    red[t] = hc[t] * W1[j * H_N + t];
    __syncthreads();
    for (int off = 128; off > 0; off >>= 1) {
        if (t < off) red[t] += red[t + off];
        __syncthreads();
    }
    if (t == 0) proj[j] = red[0];
    // zero the ct accumulator region of d_out (atomics land here in k_ct)
    if (j == 0) out[T_N + t] = 0.0f;
}

// ---------------------------------------------------------------- At = tanh(Mt@Wm + proj) @ V
// BM=64 rows/block, N=256 full, K=256 in 4 slabs of 64. 256 threads = 4 waves (2x2).
__global__ __launch_bounds__(256) void k_at(const float* __restrict__ Mt,
                                            const __bf16* __restrict__ WmT,
                                            const float* __restrict__ proj,
                                            const float* __restrict__ V,
                                            float* __restrict__ At) {
    const int t0 = blockIdx.x * 64;
    const int tid = threadIdx.x;
    const int lane = tid & 63;
    const int wid = tid >> 6;
    const int wr = wid >> 1;  // row half: rows 32*wr .. +31
    const int wc = wid & 1;   // col half: cols 128*wc .. +127

    __shared__ __align__(16) char sA[64 * 256 * 2];  // 32 KB, [row][k] bf16, XOR-swizzled
    __shared__ __align__(16) char sB[256 * 64 * 2];  // 32 KB, [n][kk] bf16, XOR-swizzled
    __shared__ float at_lds[64];

    if (tid < 64) at_lds[tid] = 0.0f;

    // ---- stage A once: 64 rows x 256 k, fp32 -> bf16
#pragma unroll
    for (int it = 0; it < 16; ++it) {
        int q = tid + 256 * it;       // float4 index
        int row = q >> 6;             // 64 float4 per row
        int kp = (q & 63) << 2;
        int t = t0 + row;
        float4 v = make_float4(0.f, 0.f, 0.f, 0.f);
        if (t < T_N) v = *(const float4*)(Mt + (size_t)t * H_N + kp);
        bf16x4 b4;
        b4[0] = (__bf16)v.x; b4[1] = (__bf16)v.y; b4[2] = (__bf16)v.z; b4[3] = (__bf16)v.w;
        int off = (row * 512 + kp * 2) ^ ((row & 7) << 4);
        *(bf16x4*)(sA + off) = b4;
    }

    f32x4 acc[2][8];
#pragma unroll
    for (int a = 0; a < 2; ++a)
#pragma unroll
        for (int b = 0; b < 8; ++b) {
            f32x4 z = {0.f, 0.f, 0.f, 0.f};
            acc[a][b] = z;
        }

    for (int s = 0; s < 4; ++s) {
        const int kk0 = s * 64;
        __syncthreads();  // sB reads of previous slab done
        // ---- stage B slab: WmT[n][kk0..kk0+63] -> sB[n][0..63]
#pragma unroll
        for (int it = 0; it < 8; ++it) {
            int u = tid + 256 * it;
            int n = u >> 3;
            int ko = (u & 7) << 3;
            bf16x8 v = *(const bf16x8*)(WmT + n * H_N + kk0 + ko);
            int off = (n * 128 + ko * 2) ^ ((n & 7) << 4);
            *(bf16x8*)(sB + off) = v;
        }
        __syncthreads();
        // ---- MFMA over this slab
#pragma unroll
        for (int kk = 0; kk < 64; kk += 32) {
            bf16x8 afrag[2];
            const int kA = kk0 + kk + ((lane >> 4) << 3);
#pragma unroll
            for (int fr = 0; fr < 2; ++fr) {
                int r = 32 * wr + 16 * fr + (lane & 15);
                int off = (r * 512 + kA * 2) ^ ((r & 7) << 4);
                afrag[fr] = *(const bf16x8*)(sA + off);
            }
            const int kB = kk + ((lane >> 4) << 3);
#pragma unroll
            for (int fc = 0; fc < 8; ++fc) {
                int n = 128 * wc + 16 * fc + (lane & 15);
                int off = (n * 128 + kB * 2) ^ ((n & 7) << 4);
                bf16x8 bfrag = *(const bf16x8*)(sB + off);
                acc[0][fc] = __builtin_amdgcn_mfma_f32_16x16x32_bf16(afrag[0], bfrag, acc[0][fc], 0, 0, 0);
                acc[1][fc] = __builtin_amdgcn_mfma_f32_16x16x32_bf16(afrag[1], bfrag, acc[1][fc], 0, 0, 0);
            }
        }
    }

    // ---- epilogue: At[t] = sum_j tanh(y[t][j] + proj[j]) * V[j]
    float pj[8], vj[8];
#pragma unroll
    for (int fc = 0; fc < 8; ++fc) {
        int n = 128 * wc + 16 * fc + (lane & 15);
        pj[fc] = proj[n];
        vj[fc] = V[n];
    }
#pragma unroll
    for (int fr = 0; fr < 2; ++fr) {
#pragma unroll
        for (int i = 0; i < 4; ++i) {
            float p = 0.0f;
#pragma unroll
            for (int fc = 0; fc < 8; ++fc)
                p += tanhf(acc[fr][fc][i] + pj[fc]) * vj[fc];
            // reduce across the 16 lanes sharing this row (different cols)
            p += __shfl_xor(p, 1);
            p += __shfl_xor(p, 2);
            p += __shfl_xor(p, 4);
            p += __shfl_xor(p, 8);
            if ((lane & 15) == 0)
                atomicAdd(&at_lds[32 * wr + 16 * fr + ((lane >> 4) << 2) + i], p);
        }
    }
    __syncthreads();
    if (tid < 64) {
        int t = t0 + tid;
        if (t < T_N) At[t] = at_lds[tid];
    }
}

// ---------------------------------------------------------------- LSE stage 1: 256 blocks of partial (m, s)
__global__ __launch_bounds__(256) void k_lse_part(const float* __restrict__ At,
                                                  float2* __restrict__ part) {
    const int tid = threadIdx.x;
    const int gid = blockIdx.x * 256 + tid;
    float m = -INFINITY, s = 0.0f;
    for (int i = gid; i < T_N; i += 256 * 256) {
        float x = At[i];
        if (x > m) { s = s * expf(m - x) + 1.0f; m = x; }
        else s += expf(x - m);
    }
    __shared__ float ms[256], ss[256];
    ms[tid] = m; ss[tid] = s;
    __syncthreads();
    for (int off = 128; off > 0; off >>= 1) {
        if (tid < off) {
            float m2 = ms[tid + off], s2 = ss[tid + off];
            float M = fmaxf(ms[tid], m2);
            ss[tid] = ss[tid] * expf(ms[tid] - M) + s2 * expf(m2 - M);
            ms[tid] = M;
        }
        __syncthreads();
    }
    if (tid == 0) part[blockIdx.x] = make_float2(ms[0], ss[0]);
}

// ---------------------------------------------------------------- LSE stage 2: combine 256 partials
__global__ __launch_bounds__(256) void k_lse_final(const float2* __restrict__ part,
                                                   float* __restrict__ lse) {
    const int tid = threadIdx.x;
    __shared__ float ms[256], ss[256];
    float2 p = part[tid];
    ms[tid] = p.x; ss[tid] = p.y;
    __syncthreads();
    for (int off = 128; off > 0; off >>= 1) {
        if (tid < off) {
            float m2 = ms[tid + off], s2 = ss[tid + off];
            float M = fmaxf(ms[tid], m2);
            ss[tid] = ss[tid] * expf(ms[tid] - M) + s2 * expf(m2 - M);
            ms[tid] = M;
        }
        __syncthreads();
    }
    if (tid == 0) *lse = ms[0] + logf(ss[0]);
}

// ---------------------------------------------------------------- alphat write + ct = alphat @ Mt
// 64 rows per block; thread tid owns column tid; one atomicAdd per column per block.
__global__ __launch_bounds__(256) void k_ct(const float* __restrict__ Mt,
                                            const float* __restrict__ At,
                                            const float* __restrict__ lse,
                                            float* __restrict__ out) {
    const float L = *lse;
    const int tid = threadIdx.x;
    const int t0 = blockIdx.x * 64;
    __shared__ float al[64];
    if (tid < 64) {
        int t = t0 + tid;
        float a = 0.0f;
        if (t < T_N) { a = At[t] - L; out[t] = a; }
        al[tid] = a;
    }
    __syncthreads();
    float acc = 0.0f;
    const int rmax = min(64, T_N - t0);
    for (int r = 0; r < rmax; ++r)
        acc += al[r] * Mt[(size_t)(t0 + r) * H_N + tid];
    atomicAdd(&out[T_N + tid], acc);
}

// ----------------------------------------------------------------
extern "C" void kernel_launch(void* const* d_in, const int* in_sizes, int n_in,
                              void* d_out, int out_size, void* d_ws, size_t ws_size,
                              hipStream_t stream) {
    const float* inputs = (const float*)d_in[0];  // (T, H)
    const float* hc     = (const float*)d_in[1];  // (1, H)
    const float* Wm     = (const float*)d_in[2];  // (H, H)
    const float* V      = (const float*)d_in[3];  // (H, 1)
    const float* W1     = (const float*)d_in[4];  // (H, H)
    float* out = (float*)d_out;                   // [alphat (T) | ct (H)]

    char* ws = (char*)d_ws;
    __bf16* WmT = (__bf16*)ws;
    float* proj = (float*)(ws + 131072);
    float* At   = (float*)(ws + 132096);
    float2* part = (float2*)(ws + 532096);
    float* lse  = (float*)(ws + 534144);

    const int nblk = (T_N + 63) / 64;  // 1563

    k_prep<<<256, 256, 0, stream>>>(Wm, hc, W1, WmT, proj, out);
    k_at<<<nblk, 256, 0, stream>>>(inputs, WmT, proj, V, At);
    k_lse_part<<<256, 256, 0, stream>>>(At, part);
    k_lse_final<<<1, 256, 0, stream>>>(part, lse);
    k_ct<<<nblk, 256, 0, stream>>>(inputs, At, lse, out);
}